// Round 9
// baseline (58.255 us; speedup 1.0000x reference)
//
#include <hip/hip_runtime.h>

// CRF NLL fused kernel v6: 1 wave per block, 4 elems per block, grid 2048 (8 blocks/CU).
// Phase A (verified math): emissions e=(X·W^T)/ln2 via bf16 MFMA, 5 tiles (80 rows),
//   bf16-packed u32 words into LDS [80][20] (stride 20 words = 16B-aligned rows).
// Phase B (verified math): MFMA-matvec recursion, B-cols 0..3 = this block's elems
//   (cols 4..15 replicate col c&3 harmlessly); all 20 e-steps prefetched to registers.
// No inline asm (cvtpk asm NaN'd rounds 3/6). T read from global (L2-resident).

typedef float f32x4 __attribute__((ext_vector_type(4)));
typedef __bf16 bf16x8 __attribute__((ext_vector_type(8)));
typedef unsigned int u32x4 __attribute__((ext_vector_type(4)));

#define C_SCALE 1.4426950408889634f  // 1/ln2
#define LN2 0.6931471805599453f
#define NEGF -3.0e38f

__device__ __forceinline__ unsigned short f2bf(float f) {
    unsigned u = __float_as_uint(f);
    u += 0x7fffu + ((u >> 16) & 1u);   // RNE
    return (unsigned short)(u >> 16);
}

__device__ __forceinline__ float lo16f(unsigned u) { return __uint_as_float(u << 16); }
__device__ __forceinline__ float hi16f(unsigned u) { return __uint_as_float(u & 0xFFFF0000u); }

union ABu { unsigned int w[4]; bf16x8 b; unsigned short u[8]; };

__device__ __forceinline__ bf16x8 pack_bf8(f32x4 a, f32x4 b) {
    ABu r;
    r.u[0] = f2bf(a[0]); r.u[1] = f2bf(a[1]); r.u[2] = f2bf(a[2]); r.u[3] = f2bf(a[3]);
    r.u[4] = f2bf(b[0]); r.u[5] = f2bf(b[1]); r.u[6] = f2bf(b[2]); r.u[7] = f2bf(b[3]);
    return r.b;
}

__global__ __launch_bounds__(64) void crf_kernel(
    const float* __restrict__ X, const int* __restrict__ Y,
    const float* __restrict__ W, const float* __restrict__ T,
    float* __restrict__ out)
{
    __shared__ unsigned e_lds[80 * 20];   // packed (col j | col j+16<<16), row stride 20 words

    const int l  = threadIdx.x;           // single wave
    const int c0 = l & 15, kg = l >> 4;

    // ---- W as bf16 B-fragments (verified): B[k][col]=W[col][k], col=lane&15, k=kg*8+j ----
    ABu bfrag[4][2];
    {
        const int koff = kg * 8;
        #pragma unroll
        for (int kk = 0; kk < 4; ++kk) {
            #pragma unroll
            for (int nt = 0; nt < 2; ++nt) {
                const int col = nt * 16 + c0;
                ABu f;
                if (col < 26) {
                    const float* wp = W + col * 128 + kk * 32 + koff;
                    f32x4 w0 = *(const f32x4*)wp;
                    f32x4 w1 = *(const f32x4*)(wp + 4);
                    f.b = pack_bf8(w0, w1);
                } else {
                    f.w[0] = f.w[1] = f.w[2] = f.w[3] = 0u;
                }
                bfrag[kk][nt] = f;
            }
        }
    }

    // ---- Phase A: 5 tiles = 80 rows (4 elems x 20 steps), verified math ----
    for (int t = 0; t < 5; ++t) {
        const float* xp = X + ((long)blockIdx.x * 80 + t * 16 + c0) * 128 + kg * 8;
        f32x4 acc0 = {0.f,0.f,0.f,0.f}, acc1 = {0.f,0.f,0.f,0.f};
        #pragma unroll
        for (int kk = 0; kk < 4; ++kk) {
            f32x4 x0 = *(const f32x4*)(xp + kk * 32);
            f32x4 x1 = *(const f32x4*)(xp + kk * 32 + 4);
            bf16x8 a = pack_bf8(x0, x1);
            acc0 = __builtin_amdgcn_mfma_f32_16x16x32_bf16(a, bfrag[kk][0].b, acc0, 0, 0, 0);
            acc1 = __builtin_amdgcn_mfma_f32_16x16x32_bf16(a, bfrag[kk][1].b, acc1, 0, 0, 0);
        }
        // C/D: col=lane&15, row=kg*4+i  [verified]
        #pragma unroll
        for (int i = 0; i < 4; ++i) {
            const int rr = t * 16 + kg * 4 + i;
            const unsigned wlo = f2bf(acc0[i] * C_SCALE);
            const unsigned whi = f2bf(acc1[i] * C_SCALE);
            e_lds[rr * 20 + c0] = (whi << 16) | wlo;
        }
    }
    __syncthreads();

    // ---- Phase B: MFMA-matvec recursion (verified math), cols 0..3 real ----
    const int g = kg, c = c0;
    const int ce = c & 3;                 // clamped elem index (dummy cols replicate)

    // A-fragments: A[m][k'] = E[pi(k')][m], pi(8g+jj) = 4g+(jj&3)+16*(jj>>2)  [verified]
    ABu A0, A1;
    #pragma unroll
    for (int jj = 0; jj < 8; ++jj) {
        const int kp = 4 * g + (jj & 3) + ((jj >> 2) << 4);
        float v0 = 0.f, v1 = 0.f;
        if (kp < 26) {
            v0 = __builtin_amdgcn_exp2f(T[kp * 26 + c] * C_SCALE);
            if (16 + c < 26) v1 = __builtin_amdgcn_exp2f(T[kp * 26 + 16 + c] * C_SCALE);
        }
        A0.u[jj] = f2bf(v0);
        A1.u[jj] = f2bf(v1);
    }

    const bool ok0 = (16 + 4 * g + 0) < 26;
    const bool ok1 = (16 + 4 * g + 1) < 26;
    const bool ok2 = (16 + 4 * g + 2) < 26;
    const bool ok3 = (16 + 4 * g + 3) < 26;

    // prefetch all 20 timesteps (word i = cols (4g+i, 4g+i+16)) — 16B-aligned ds_read_b128
    u32x4 ev[20];
    #pragma unroll
    for (int m = 0; m < 20; ++m)
        ev[m] = *(const u32x4*)&e_lds[(ce * 20 + m) * 20 + 4 * g];

    f32x4 s0, s1;
    #pragma unroll
    for (int i = 0; i < 4; ++i) { s0[i] = lo16f(ev[0][i]); s1[i] = hi16f(ev[0][i]); }
    if (!ok0) s1[0] = NEGF;
    if (!ok1) s1[1] = NEGF;
    if (!ok2) s1[2] = NEGF;
    if (!ok3) s1[3] = NEGF;

    const f32x4 z = {0.f, 0.f, 0.f, 0.f};
    #pragma unroll
    for (int m = 0; m < 19; ++m) {
        float mx = fmaxf(fmaxf(fmaxf(s0[0], s0[1]), fmaxf(s0[2], s0[3])),
                         fmaxf(fmaxf(s1[0], s1[1]), fmaxf(s1[2], s1[3])));
        mx = fmaxf(mx, __shfl_xor(mx, 16, 64));
        mx = fmaxf(mx, __shfl_xor(mx, 32, 64));
        ABu B;
        B.u[0] = f2bf(__builtin_amdgcn_exp2f(s0[0] - mx));
        B.u[1] = f2bf(__builtin_amdgcn_exp2f(s0[1] - mx));
        B.u[2] = f2bf(__builtin_amdgcn_exp2f(s0[2] - mx));
        B.u[3] = f2bf(__builtin_amdgcn_exp2f(s0[3] - mx));
        B.u[4] = f2bf(__builtin_amdgcn_exp2f(s1[0] - mx));
        B.u[5] = f2bf(__builtin_amdgcn_exp2f(s1[1] - mx));
        B.u[6] = f2bf(__builtin_amdgcn_exp2f(s1[2] - mx));
        B.u[7] = f2bf(__builtin_amdgcn_exp2f(s1[3] - mx));
        f32x4 D0 = __builtin_amdgcn_mfma_f32_16x16x32_bf16(A0.b, B.b, z, 0, 0, 0);
        f32x4 D1 = __builtin_amdgcn_mfma_f32_16x16x32_bf16(A1.b, B.b, z, 0, 0, 0);
        #pragma unroll
        for (int i = 0; i < 4; ++i)
            s0[i] = mx + __builtin_amdgcn_logf(D0[i]) + lo16f(ev[m + 1][i]);
        s1[0] = ok0 ? (mx + __builtin_amdgcn_logf(D1[0]) + hi16f(ev[m + 1][0])) : NEGF;
        s1[1] = ok1 ? (mx + __builtin_amdgcn_logf(D1[1]) + hi16f(ev[m + 1][1])) : NEGF;
        s1[2] = ok2 ? (mx + __builtin_amdgcn_logf(D1[2]) + hi16f(ev[m + 1][2])) : NEGF;
        s1[3] = ok3 ? (mx + __builtin_amdgcn_logf(D1[3]) + hi16f(ev[m + 1][3])) : NEGF;
    }

    // logZ per column c (butterfly over g only: xor 16, 32)
    float mx2 = fmaxf(fmaxf(fmaxf(s0[0], s0[1]), fmaxf(s0[2], s0[3])),
                      fmaxf(fmaxf(s1[0], s1[1]), fmaxf(s1[2], s1[3])));
    mx2 = fmaxf(mx2, __shfl_xor(mx2, 16, 64));
    mx2 = fmaxf(mx2, __shfl_xor(mx2, 32, 64));
    float sm = __builtin_amdgcn_exp2f(s0[0] - mx2) + __builtin_amdgcn_exp2f(s0[1] - mx2)
             + __builtin_amdgcn_exp2f(s0[2] - mx2) + __builtin_amdgcn_exp2f(s0[3] - mx2)
             + __builtin_amdgcn_exp2f(s1[0] - mx2) + __builtin_amdgcn_exp2f(s1[1] - mx2)
             + __builtin_amdgcn_exp2f(s1[2] - mx2) + __builtin_amdgcn_exp2f(s1[3] - mx2);
    sm += __shfl_xor(sm, 16, 64);
    sm += __shfl_xor(sm, 32, 64);
    const float logZ2 = mx2 + __builtin_amdgcn_logf(sm);

    // node + edge: lane (g, c<4) covers elem c's timesteps 5g..5g+4
    float v = 0.f;
    if (c < 4) {
        const int ebase = (blockIdx.x * 4 + c) * 20;
        float nd2 = 0.f, edn = 0.f;
        int y[6];
        #pragma unroll
        for (int t = 0; t < 5; ++t) y[t] = Y[ebase + 5 * g + t];
        y[5] = (g < 3) ? Y[ebase + 5 * g + 5] : 0;
        #pragma unroll
        for (int t = 0; t < 5; ++t) {
            const int m = 5 * g + t;
            const unsigned wv = e_lds[(c * 20 + m) * 20 + (y[t] & 15)];
            nd2 += (y[t] < 16) ? lo16f(wv) : hi16f(wv);
            if (m < 19) edn += T[y[t] * 26 + y[t + 1]];
        }
        v = -LN2 * nd2 - edn;
        if (g == 0) v += LN2 * logZ2;
    }
    #pragma unroll
    for (int d = 1; d <= 32; d <<= 1) v += __shfl_xor(v, d, 64);
    if (l == 0) atomicAdd(out, v);
}

extern "C" void kernel_launch(void* const* d_in, const int* in_sizes, int n_in,
                              void* d_out, int out_size, void* d_ws, size_t ws_size,
                              hipStream_t stream) {
    const float* X = (const float*)d_in[0];
    const int*   Y = (const int*)d_in[1];
    const float* W = (const float*)d_in[2];
    const float* T = (const float*)d_in[3];
    float* out = (float*)d_out;

    const int rows = in_sizes[0] / 128;    // 163840
    const int nblocks = rows / 80;         // 2048 (4 elems per block)

    hipMemsetAsync(out, 0, sizeof(float), stream);
    crf_kernel<<<nblocks, 64, 0, stream>>>(X, Y, W, T, out);
}

// Round 10
// 38.417 us; speedup vs baseline: 1.5164x; 1.5164x over previous
//
#include <hip/hip_runtime.h>

// CRF NLL fused kernel v7 = round-4 verified math, phase-B chain-latency attack:
//  - emissions bf16-PACKED into LDS (u32 = col j | col j+16<<16), round-8-verified numerics
//  - wave 0 prefetches all 20 timesteps into registers (ev[20], fully unrolled chain)
//  - per-step butterfly max: 1x shfl_xor(16) + 1x permlane32_swap (VALU) instead of 2 DS ops
//  - per-step NEGF masks dropped: zero A1 pad rows give log2(0) = -inf, self-sustaining
//  - wave 1 computes node/edge potentials concurrently; waves 2-3 exit after barrier
// No inline asm (cvtpk asm NaN'd rounds 3/6).

typedef float f32x4 __attribute__((ext_vector_type(4)));
typedef __bf16 bf16x8 __attribute__((ext_vector_type(8)));
typedef unsigned int u32x4 __attribute__((ext_vector_type(4)));
typedef unsigned int u32x2 __attribute__((ext_vector_type(2)));

#define C_SCALE 1.4426950408889634f  // 1/ln2
#define LN2 0.6931471805599453f
#define NEGF (-3.0e38f)

__device__ __forceinline__ unsigned short f2bf(float f) {
    unsigned u = __float_as_uint(f);
    u += 0x7fffu + ((u >> 16) & 1u);   // RNE
    return (unsigned short)(u >> 16);
}

__device__ __forceinline__ float lo16f(unsigned u) { return __uint_as_float(u << 16); }
__device__ __forceinline__ float hi16f(unsigned u) { return __uint_as_float(u & 0xFFFF0000u); }

// max/sum over the 4 lanes {c, c+16, c+32, c+48}: xor-16 via DS shuffle,
// xor-32 via permlane32_swap (VALU pipe, replicates result to both halves).
__device__ __forceinline__ float qmax(float x) {
    float y = fmaxf(x, __shfl_xor(x, 16, 64));
    u32x2 r = __builtin_amdgcn_permlane32_swap(__float_as_uint(y), __float_as_uint(y), false, false);
    return fmaxf(__uint_as_float(r[0]), __uint_as_float(r[1]));
}
__device__ __forceinline__ float qsum(float x) {
    float y = x + __shfl_xor(x, 16, 64);
    u32x2 r = __builtin_amdgcn_permlane32_swap(__float_as_uint(y), __float_as_uint(y), false, false);
    return __uint_as_float(r[0]) + __uint_as_float(r[1]);
}

union ABu { unsigned int w[4]; bf16x8 b; unsigned short u[8]; };

__device__ __forceinline__ bf16x8 pack_bf8(f32x4 a, f32x4 b) {
    ABu r;
    r.u[0] = f2bf(a[0]); r.u[1] = f2bf(a[1]); r.u[2] = f2bf(a[2]); r.u[3] = f2bf(a[3]);
    r.u[4] = f2bf(b[0]); r.u[5] = f2bf(b[1]); r.u[6] = f2bf(b[2]); r.u[7] = f2bf(b[3]);
    return r.b;
}

__global__ __launch_bounds__(256, 2) void crf_kernel(
    const float* __restrict__ X, const int* __restrict__ Y,
    const float* __restrict__ W, const float* __restrict__ T,
    float* __restrict__ out)
{
    __shared__ unsigned e_lds[320 * 20];  // packed bf16 pairs, row stride 20 words (80B)
    __shared__ float t_lds[26 * 26];      // T natural domain

    const int tid = threadIdx.x;
    const int w   = tid >> 6;
    const int l   = tid & 63;
    const int c0  = l & 15, kg = l >> 4;

    for (int i = tid; i < 676; i += 256) t_lds[i] = T[i];

    // ---- Phase A (verified): W B-frags, 5 MFMA tiles per wave, packed store ----
    {
        ABu bfrag[4][2];
        const int koff = kg * 8;
        #pragma unroll
        for (int kk = 0; kk < 4; ++kk) {
            #pragma unroll
            for (int nt = 0; nt < 2; ++nt) {
                const int col = nt * 16 + c0;
                ABu f;
                if (col < 26) {
                    const float* wp = W + col * 128 + kk * 32 + koff;
                    f32x4 w0 = *(const f32x4*)wp;
                    f32x4 w1 = *(const f32x4*)(wp + 4);
                    f.b = pack_bf8(w0, w1);
                } else {
                    f.w[0] = f.w[1] = f.w[2] = f.w[3] = 0u;
                }
                bfrag[kk][nt] = f;
            }
        }
        const int rbase = w * 80;
        for (int t = 0; t < 5; ++t) {
            const float* xp = X + ((long)blockIdx.x * 320 + rbase + t * 16 + c0) * 128 + kg * 8;
            f32x4 acc0 = {0.f,0.f,0.f,0.f}, acc1 = {0.f,0.f,0.f,0.f};
            #pragma unroll
            for (int kk = 0; kk < 4; ++kk) {
                f32x4 x0 = *(const f32x4*)(xp + kk * 32);
                f32x4 x1 = *(const f32x4*)(xp + kk * 32 + 4);
                bf16x8 a = pack_bf8(x0, x1);
                acc0 = __builtin_amdgcn_mfma_f32_16x16x32_bf16(a, bfrag[kk][0].b, acc0, 0, 0, 0);
                acc1 = __builtin_amdgcn_mfma_f32_16x16x32_bf16(a, bfrag[kk][1].b, acc1, 0, 0, 0);
            }
            // C/D: col=lane&15, row=kg*4+i [verified]; packed word (verified round-8)
            #pragma unroll
            for (int i = 0; i < 4; ++i) {
                const int rr = rbase + t * 16 + kg * 4 + i;
                const unsigned wlo = f2bf(acc0[i] * C_SCALE);
                const unsigned whi = f2bf(acc1[i] * C_SCALE);
                e_lds[rr * 20 + c0] = (whi << 16) | wlo;
            }
        }
    }
    __syncthreads();

    const int g = l >> 4, c = l & 15;
    const int elem = blockIdx.x * 16 + c;

    // ---- Wave 1: node + edge potentials (overlap wave 0's recursion) ----
    if (w == 1) {
        const int ebase = elem * 20;
        float nd2 = 0.f, edn = 0.f;
        int y[6];
        #pragma unroll
        for (int t = 0; t < 5; ++t) y[t] = Y[ebase + 5 * g + t];
        y[5] = (g < 3) ? Y[ebase + 5 * g + 5] : 0;
        #pragma unroll
        for (int t = 0; t < 5; ++t) {
            const int m = 5 * g + t;
            const unsigned wv = e_lds[(c * 20 + m) * 20 + (y[t] & 15)];
            nd2 += (y[t] < 16) ? lo16f(wv) : hi16f(wv);
            if (m < 19) edn += t_lds[y[t] * 26 + y[t + 1]];
        }
        float v = -LN2 * nd2 - edn;
        #pragma unroll
        for (int d = 1; d <= 32; d <<= 1) v += __shfl_xor(v, d, 64);
        if (l == 0) atomicAdd(out, v);
        return;
    }
    if (w != 0) return;

    // ---- Wave 0: MFMA-matvec recursion (verified math) ----
    // A-fragments: A[m][k'] = E[pi(k')][m], pi(8g+jj) = 4g+(jj&3)+16*(jj>>2)  [verified]
    ABu A0, A1;
    #pragma unroll
    for (int jj = 0; jj < 8; ++jj) {
        const int kp = 4 * g + (jj & 3) + ((jj >> 2) << 4);
        float v0 = 0.f, v1 = 0.f;
        if (kp < 26) {
            v0 = __builtin_amdgcn_exp2f(t_lds[kp * 26 + c] * C_SCALE);
            if (16 + c < 26) v1 = __builtin_amdgcn_exp2f(t_lds[kp * 26 + 16 + c] * C_SCALE);
        }
        A0.u[jj] = f2bf(v0);
        A1.u[jj] = f2bf(v1);
    }

    // prefetch all 20 timesteps to registers (16B-aligned ds_read_b128)
    u32x4 ev[20];
    #pragma unroll
    for (int m = 0; m < 20; ++m)
        ev[m] = *(const u32x4*)&e_lds[c * 400 + m * 20 + 4 * g];

    f32x4 s0, s1;
    #pragma unroll
    for (int i = 0; i < 4; ++i) { s0[i] = lo16f(ev[0][i]); s1[i] = hi16f(ev[0][i]); }
    if (16 + 4 * g + 0 >= 26) s1[0] = NEGF;
    if (16 + 4 * g + 1 >= 26) s1[1] = NEGF;
    if (16 + 4 * g + 2 >= 26) s1[2] = NEGF;
    if (16 + 4 * g + 3 >= 26) s1[3] = NEGF;

    const f32x4 z = {0.f, 0.f, 0.f, 0.f};
    #pragma unroll
    for (int m = 0; m < 19; ++m) {
        const float mx8 = fmaxf(fmaxf(fmaxf(s0[0], s0[1]), fmaxf(s0[2], s0[3])),
                                fmaxf(fmaxf(s1[0], s1[1]), fmaxf(s1[2], s1[3])));
        const float mx = qmax(mx8);
        ABu B;
        B.u[0] = f2bf(__builtin_amdgcn_exp2f(s0[0] - mx));
        B.u[1] = f2bf(__builtin_amdgcn_exp2f(s0[1] - mx));
        B.u[2] = f2bf(__builtin_amdgcn_exp2f(s0[2] - mx));
        B.u[3] = f2bf(__builtin_amdgcn_exp2f(s0[3] - mx));
        B.u[4] = f2bf(__builtin_amdgcn_exp2f(s1[0] - mx));
        B.u[5] = f2bf(__builtin_amdgcn_exp2f(s1[1] - mx));
        B.u[6] = f2bf(__builtin_amdgcn_exp2f(s1[2] - mx));
        B.u[7] = f2bf(__builtin_amdgcn_exp2f(s1[3] - mx));
        f32x4 D0 = __builtin_amdgcn_mfma_f32_16x16x32_bf16(A0.b, B.b, z, 0, 0, 0);
        f32x4 D1 = __builtin_amdgcn_mfma_f32_16x16x32_bf16(A1.b, B.b, z, 0, 0, 0);
        // pad rows: D1 = 0 -> log2(0) = -inf, self-sustaining (no per-step masks)
        #pragma unroll
        for (int i = 0; i < 4; ++i) {
            s0[i] = mx + __builtin_amdgcn_logf(D0[i]) + lo16f(ev[m + 1][i]);
            s1[i] = mx + __builtin_amdgcn_logf(D1[i]) + hi16f(ev[m + 1][i]);
        }
    }

    // logZ per column c
    const float mxl = fmaxf(fmaxf(fmaxf(s0[0], s0[1]), fmaxf(s0[2], s0[3])),
                            fmaxf(fmaxf(s1[0], s1[1]), fmaxf(s1[2], s1[3])));
    const float mx2 = qmax(mxl);
    float sm = __builtin_amdgcn_exp2f(s0[0] - mx2) + __builtin_amdgcn_exp2f(s0[1] - mx2)
             + __builtin_amdgcn_exp2f(s0[2] - mx2) + __builtin_amdgcn_exp2f(s0[3] - mx2)
             + __builtin_amdgcn_exp2f(s1[0] - mx2) + __builtin_amdgcn_exp2f(s1[1] - mx2)
             + __builtin_amdgcn_exp2f(s1[2] - mx2) + __builtin_amdgcn_exp2f(s1[3] - mx2);
    sm = qsum(sm);
    const float logZ2 = mx2 + __builtin_amdgcn_logf(sm);

    float v = (g == 0) ? LN2 * logZ2 : 0.f;
    #pragma unroll
    for (int d = 1; d <= 32; d <<= 1) v += __shfl_xor(v, d, 64);
    if (l == 0) atomicAdd(out, v);
}

extern "C" void kernel_launch(void* const* d_in, const int* in_sizes, int n_in,
                              void* d_out, int out_size, void* d_ws, size_t ws_size,
                              hipStream_t stream) {
    const float* X = (const float*)d_in[0];
    const int*   Y = (const int*)d_in[1];
    const float* W = (const float*)d_in[2];
    const float* T = (const float*)d_in[3];
    float* out = (float*)d_out;

    const int B = in_sizes[1] / 20;        // 8192
    const int nblocks = B / 16;            // 512

    hipMemsetAsync(out, 0, sizeof(float), stream);
    crf_kernel<<<nblocks, 256, 0, stream>>>(X, Y, W, T, out);
}

// Round 11
// 38.377 us; speedup vs baseline: 1.5180x; 1.0011x over previous
//
#include <hip/hip_runtime.h>

// CRF NLL fused kernel v8 = v7 EXACTLY, but phase A executed TWICE (idempotent probe).
// Purpose: measure T_A directly as (dur_v8 - dur_v7); asm memory fence defeats DSE/CSE
// so rep 0 really executes. All math verified rounds 4/8/10.

typedef float f32x4 __attribute__((ext_vector_type(4)));
typedef __bf16 bf16x8 __attribute__((ext_vector_type(8)));
typedef unsigned int u32x4 __attribute__((ext_vector_type(4)));
typedef unsigned int u32x2 __attribute__((ext_vector_type(2)));

#define C_SCALE 1.4426950408889634f  // 1/ln2
#define LN2 0.6931471805599453f
#define NEGF (-3.0e38f)

__device__ __forceinline__ unsigned short f2bf(float f) {
    unsigned u = __float_as_uint(f);
    u += 0x7fffu + ((u >> 16) & 1u);   // RNE
    return (unsigned short)(u >> 16);
}

__device__ __forceinline__ float lo16f(unsigned u) { return __uint_as_float(u << 16); }
__device__ __forceinline__ float hi16f(unsigned u) { return __uint_as_float(u & 0xFFFF0000u); }

__device__ __forceinline__ float qmax(float x) {
    float y = fmaxf(x, __shfl_xor(x, 16, 64));
    u32x2 r = __builtin_amdgcn_permlane32_swap(__float_as_uint(y), __float_as_uint(y), false, false);
    return fmaxf(__uint_as_float(r[0]), __uint_as_float(r[1]));
}
__device__ __forceinline__ float qsum(float x) {
    float y = x + __shfl_xor(x, 16, 64);
    u32x2 r = __builtin_amdgcn_permlane32_swap(__float_as_uint(y), __float_as_uint(y), false, false);
    return __uint_as_float(r[0]) + __uint_as_float(r[1]);
}

union ABu { unsigned int w[4]; bf16x8 b; unsigned short u[8]; };

__device__ __forceinline__ bf16x8 pack_bf8(f32x4 a, f32x4 b) {
    ABu r;
    r.u[0] = f2bf(a[0]); r.u[1] = f2bf(a[1]); r.u[2] = f2bf(a[2]); r.u[3] = f2bf(a[3]);
    r.u[4] = f2bf(b[0]); r.u[5] = f2bf(b[1]); r.u[6] = f2bf(b[2]); r.u[7] = f2bf(b[3]);
    return r.b;
}

__global__ __launch_bounds__(256, 2) void crf_kernel(
    const float* __restrict__ X, const int* __restrict__ Y,
    const float* __restrict__ W, const float* __restrict__ T,
    float* __restrict__ out)
{
    __shared__ unsigned e_lds[320 * 20];  // packed bf16 pairs, row stride 20 words (80B)
    __shared__ float t_lds[26 * 26];      // T natural domain

    const int tid = threadIdx.x;
    const int w   = tid >> 6;
    const int l   = tid & 63;
    const int c0  = l & 15, kg = l >> 4;

    for (int i = tid; i < 676; i += 256) t_lds[i] = T[i];

    // ---- Phase A (verified): W B-frags once; tile pass executed TWICE (probe) ----
    {
        ABu bfrag[4][2];
        const int koff = kg * 8;
        #pragma unroll
        for (int kk = 0; kk < 4; ++kk) {
            #pragma unroll
            for (int nt = 0; nt < 2; ++nt) {
                const int col = nt * 16 + c0;
                ABu f;
                if (col < 26) {
                    const float* wp = W + col * 128 + kk * 32 + koff;
                    f32x4 w0 = *(const f32x4*)wp;
                    f32x4 w1 = *(const f32x4*)(wp + 4);
                    f.b = pack_bf8(w0, w1);
                } else {
                    f.w[0] = f.w[1] = f.w[2] = f.w[3] = 0u;
                }
                bfrag[kk][nt] = f;
            }
        }
        const int rbase = w * 80;
        #pragma unroll 1
        for (int rep = 0; rep < 2; ++rep) {
            for (int t = 0; t < 5; ++t) {
                const float* xp = X + ((long)blockIdx.x * 320 + rbase + t * 16 + c0) * 128 + kg * 8;
                f32x4 acc0 = {0.f,0.f,0.f,0.f}, acc1 = {0.f,0.f,0.f,0.f};
                #pragma unroll
                for (int kk = 0; kk < 4; ++kk) {
                    f32x4 x0 = *(const f32x4*)(xp + kk * 32);
                    f32x4 x1 = *(const f32x4*)(xp + kk * 32 + 4);
                    bf16x8 a = pack_bf8(x0, x1);
                    acc0 = __builtin_amdgcn_mfma_f32_16x16x32_bf16(a, bfrag[kk][0].b, acc0, 0, 0, 0);
                    acc1 = __builtin_amdgcn_mfma_f32_16x16x32_bf16(a, bfrag[kk][1].b, acc1, 0, 0, 0);
                }
                // C/D: col=lane&15, row=kg*4+i [verified]; packed word (verified round-8)
                #pragma unroll
                for (int i = 0; i < 4; ++i) {
                    const int rr = rbase + t * 16 + kg * 4 + i;
                    const unsigned wlo = f2bf(acc0[i] * C_SCALE);
                    const unsigned whi = f2bf(acc1[i] * C_SCALE);
                    e_lds[rr * 20 + c0] = (whi << 16) | wlo;
                }
            }
            asm volatile("" ::: "memory");   // defeat DSE/CSE: rep 0 must fully execute
        }
    }
    __syncthreads();

    const int g = l >> 4, c = l & 15;
    const int elem = blockIdx.x * 16 + c;

    // ---- Wave 1: node + edge potentials ----
    if (w == 1) {
        const int ebase = elem * 20;
        float nd2 = 0.f, edn = 0.f;
        int y[6];
        #pragma unroll
        for (int t = 0; t < 5; ++t) y[t] = Y[ebase + 5 * g + t];
        y[5] = (g < 3) ? Y[ebase + 5 * g + 5] : 0;
        #pragma unroll
        for (int t = 0; t < 5; ++t) {
            const int m = 5 * g + t;
            const unsigned wv = e_lds[(c * 20 + m) * 20 + (y[t] & 15)];
            nd2 += (y[t] < 16) ? lo16f(wv) : hi16f(wv);
            if (m < 19) edn += t_lds[y[t] * 26 + y[t + 1]];
        }
        float v = -LN2 * nd2 - edn;
        #pragma unroll
        for (int d = 1; d <= 32; d <<= 1) v += __shfl_xor(v, d, 64);
        if (l == 0) atomicAdd(out, v);
        return;
    }
    if (w != 0) return;

    // ---- Wave 0: MFMA-matvec recursion (verified) ----
    ABu A0, A1;
    #pragma unroll
    for (int jj = 0; jj < 8; ++jj) {
        const int kp = 4 * g + (jj & 3) + ((jj >> 2) << 4);
        float v0 = 0.f, v1 = 0.f;
        if (kp < 26) {
            v0 = __builtin_amdgcn_exp2f(t_lds[kp * 26 + c] * C_SCALE);
            if (16 + c < 26) v1 = __builtin_amdgcn_exp2f(t_lds[kp * 26 + 16 + c] * C_SCALE);
        }
        A0.u[jj] = f2bf(v0);
        A1.u[jj] = f2bf(v1);
    }

    u32x4 ev[20];
    #pragma unroll
    for (int m = 0; m < 20; ++m)
        ev[m] = *(const u32x4*)&e_lds[c * 400 + m * 20 + 4 * g];

    f32x4 s0, s1;
    #pragma unroll
    for (int i = 0; i < 4; ++i) { s0[i] = lo16f(ev[0][i]); s1[i] = hi16f(ev[0][i]); }
    if (16 + 4 * g + 0 >= 26) s1[0] = NEGF;
    if (16 + 4 * g + 1 >= 26) s1[1] = NEGF;
    if (16 + 4 * g + 2 >= 26) s1[2] = NEGF;
    if (16 + 4 * g + 3 >= 26) s1[3] = NEGF;

    const f32x4 z = {0.f, 0.f, 0.f, 0.f};
    #pragma unroll
    for (int m = 0; m < 19; ++m) {
        const float mx8 = fmaxf(fmaxf(fmaxf(s0[0], s0[1]), fmaxf(s0[2], s0[3])),
                                fmaxf(fmaxf(s1[0], s1[1]), fmaxf(s1[2], s1[3])));
        const float mx = qmax(mx8);
        ABu B;
        B.u[0] = f2bf(__builtin_amdgcn_exp2f(s0[0] - mx));
        B.u[1] = f2bf(__builtin_amdgcn_exp2f(s0[1] - mx));
        B.u[2] = f2bf(__builtin_amdgcn_exp2f(s0[2] - mx));
        B.u[3] = f2bf(__builtin_amdgcn_exp2f(s0[3] - mx));
        B.u[4] = f2bf(__builtin_amdgcn_exp2f(s1[0] - mx));
        B.u[5] = f2bf(__builtin_amdgcn_exp2f(s1[1] - mx));
        B.u[6] = f2bf(__builtin_amdgcn_exp2f(s1[2] - mx));
        B.u[7] = f2bf(__builtin_amdgcn_exp2f(s1[3] - mx));
        f32x4 D0 = __builtin_amdgcn_mfma_f32_16x16x32_bf16(A0.b, B.b, z, 0, 0, 0);
        f32x4 D1 = __builtin_amdgcn_mfma_f32_16x16x32_bf16(A1.b, B.b, z, 0, 0, 0);
        #pragma unroll
        for (int i = 0; i < 4; ++i) {
            s0[i] = mx + __builtin_amdgcn_logf(D0[i]) + lo16f(ev[m + 1][i]);
            s1[i] = mx + __builtin_amdgcn_logf(D1[i]) + hi16f(ev[m + 1][i]);
        }
    }

    const float mxl = fmaxf(fmaxf(fmaxf(s0[0], s0[1]), fmaxf(s0[2], s0[3])),
                            fmaxf(fmaxf(s1[0], s1[1]), fmaxf(s1[2], s1[3])));
    const float mx2 = qmax(mxl);
    float sm = __builtin_amdgcn_exp2f(s0[0] - mx2) + __builtin_amdgcn_exp2f(s0[1] - mx2)
             + __builtin_amdgcn_exp2f(s0[2] - mx2) + __builtin_amdgcn_exp2f(s0[3] - mx2)
             + __builtin_amdgcn_exp2f(s1[0] - mx2) + __builtin_amdgcn_exp2f(s1[1] - mx2)
             + __builtin_amdgcn_exp2f(s1[2] - mx2) + __builtin_amdgcn_exp2f(s1[3] - mx2);
    sm = qsum(sm);
    const float logZ2 = mx2 + __builtin_amdgcn_logf(sm);

    float v = (g == 0) ? LN2 * logZ2 : 0.f;
    #pragma unroll
    for (int d = 1; d <= 32; d <<= 1) v += __shfl_xor(v, d, 64);
    if (l == 0) atomicAdd(out, v);
}

extern "C" void kernel_launch(void* const* d_in, const int* in_sizes, int n_in,
                              void* d_out, int out_size, void* d_ws, size_t ws_size,
                              hipStream_t stream) {
    const float* X = (const float*)d_in[0];
    const int*   Y = (const int*)d_in[1];
    const float* W = (const float*)d_in[2];
    const float* T = (const float*)d_in[3];
    float* out = (float*)d_out;

    const int B = in_sizes[1] / 20;        // 8192
    const int nblocks = B / 16;            // 512

    hipMemsetAsync(out, 0, sizeof(float), stream);
    crf_kernel<<<nblocks, 256, 0, stream>>>(X, Y, W, T, out);
}

// Round 12
// 30.128 us; speedup vs baseline: 1.9336x; 1.2738x over previous
//
#include <hip/hip_runtime.h>

// CRF NLL v9 = v7 verified math, ZERO global atomics:
//   main kernel: per-block partial (wave0 logZ + wave1 node/edge, combined via LDS)
//                -> plain store to d_ws[bid]  (512 distinct addresses, no contention)
//   reduce kernel: 1 block x 256 sums the 512 partials -> out[0] (plain store).
// Theory: 1024 same-address device atomics serialized at ~20ns each = the ~20 µs tail.
// No inline asm in math paths (cvtpk asm NaN'd rounds 3/6).

typedef float f32x4 __attribute__((ext_vector_type(4)));
typedef __bf16 bf16x8 __attribute__((ext_vector_type(8)));
typedef unsigned int u32x4 __attribute__((ext_vector_type(4)));
typedef unsigned int u32x2 __attribute__((ext_vector_type(2)));

#define C_SCALE 1.4426950408889634f  // 1/ln2
#define LN2 0.6931471805599453f
#define NEGF (-3.0e38f)

__device__ __forceinline__ unsigned short f2bf(float f) {
    unsigned u = __float_as_uint(f);
    u += 0x7fffu + ((u >> 16) & 1u);   // RNE
    return (unsigned short)(u >> 16);
}

__device__ __forceinline__ float lo16f(unsigned u) { return __uint_as_float(u << 16); }
__device__ __forceinline__ float hi16f(unsigned u) { return __uint_as_float(u & 0xFFFF0000u); }

__device__ __forceinline__ float qmax(float x) {
    float y = fmaxf(x, __shfl_xor(x, 16, 64));
    u32x2 r = __builtin_amdgcn_permlane32_swap(__float_as_uint(y), __float_as_uint(y), false, false);
    return fmaxf(__uint_as_float(r[0]), __uint_as_float(r[1]));
}
__device__ __forceinline__ float qsum(float x) {
    float y = x + __shfl_xor(x, 16, 64);
    u32x2 r = __builtin_amdgcn_permlane32_swap(__float_as_uint(y), __float_as_uint(y), false, false);
    return __uint_as_float(r[0]) + __uint_as_float(r[1]);
}

union ABu { unsigned int w[4]; bf16x8 b; unsigned short u[8]; };

__device__ __forceinline__ bf16x8 pack_bf8(f32x4 a, f32x4 b) {
    ABu r;
    r.u[0] = f2bf(a[0]); r.u[1] = f2bf(a[1]); r.u[2] = f2bf(a[2]); r.u[3] = f2bf(a[3]);
    r.u[4] = f2bf(b[0]); r.u[5] = f2bf(b[1]); r.u[6] = f2bf(b[2]); r.u[7] = f2bf(b[3]);
    return r.b;
}

__global__ __launch_bounds__(256, 2) void crf_kernel(
    const float* __restrict__ X, const int* __restrict__ Y,
    const float* __restrict__ W, const float* __restrict__ T,
    float* __restrict__ part)
{
    __shared__ unsigned e_lds[320 * 20];  // packed bf16 pairs, row stride 20 words (80B)
    __shared__ float t_lds[26 * 26];      // T natural domain
    __shared__ float red1;                // wave-1 partial

    const int tid = threadIdx.x;
    const int w   = tid >> 6;
    const int l   = tid & 63;
    const int c0  = l & 15, kg = l >> 4;

    for (int i = tid; i < 676; i += 256) t_lds[i] = T[i];

    // ---- Phase A (verified): W B-frags, 5 MFMA tiles per wave, packed store ----
    {
        ABu bfrag[4][2];
        const int koff = kg * 8;
        #pragma unroll
        for (int kk = 0; kk < 4; ++kk) {
            #pragma unroll
            for (int nt = 0; nt < 2; ++nt) {
                const int col = nt * 16 + c0;
                ABu f;
                if (col < 26) {
                    const float* wp = W + col * 128 + kk * 32 + koff;
                    f32x4 w0 = *(const f32x4*)wp;
                    f32x4 w1 = *(const f32x4*)(wp + 4);
                    f.b = pack_bf8(w0, w1);
                } else {
                    f.w[0] = f.w[1] = f.w[2] = f.w[3] = 0u;
                }
                bfrag[kk][nt] = f;
            }
        }
        const int rbase = w * 80;
        for (int t = 0; t < 5; ++t) {
            const float* xp = X + ((long)blockIdx.x * 320 + rbase + t * 16 + c0) * 128 + kg * 8;
            f32x4 acc0 = {0.f,0.f,0.f,0.f}, acc1 = {0.f,0.f,0.f,0.f};
            #pragma unroll
            for (int kk = 0; kk < 4; ++kk) {
                f32x4 x0 = *(const f32x4*)(xp + kk * 32);
                f32x4 x1 = *(const f32x4*)(xp + kk * 32 + 4);
                bf16x8 a = pack_bf8(x0, x1);
                acc0 = __builtin_amdgcn_mfma_f32_16x16x32_bf16(a, bfrag[kk][0].b, acc0, 0, 0, 0);
                acc1 = __builtin_amdgcn_mfma_f32_16x16x32_bf16(a, bfrag[kk][1].b, acc1, 0, 0, 0);
            }
            // C/D: col=lane&15, row=kg*4+i [verified]; packed word (verified round-8)
            #pragma unroll
            for (int i = 0; i < 4; ++i) {
                const int rr = rbase + t * 16 + kg * 4 + i;
                const unsigned wlo = f2bf(acc0[i] * C_SCALE);
                const unsigned whi = f2bf(acc1[i] * C_SCALE);
                e_lds[rr * 20 + c0] = (whi << 16) | wlo;
            }
        }
    }
    __syncthreads();

    const int g = l >> 4, c = l & 15;
    const int elem = blockIdx.x * 16 + c;

    float myv = 0.f;   // wave-0 lanes: replicated logZ sum after reduce

    // ---- Wave 1: node + edge potentials ----
    if (w == 1) {
        const int ebase = elem * 20;
        float nd2 = 0.f, edn = 0.f;
        int y[6];
        #pragma unroll
        for (int t = 0; t < 5; ++t) y[t] = Y[ebase + 5 * g + t];
        y[5] = (g < 3) ? Y[ebase + 5 * g + 5] : 0;
        #pragma unroll
        for (int t = 0; t < 5; ++t) {
            const int m = 5 * g + t;
            const unsigned wv = e_lds[(c * 20 + m) * 20 + (y[t] & 15)];
            nd2 += (y[t] < 16) ? lo16f(wv) : hi16f(wv);
            if (m < 19) edn += t_lds[y[t] * 26 + y[t + 1]];
        }
        float v = -LN2 * nd2 - edn;
        #pragma unroll
        for (int d = 1; d <= 32; d <<= 1) v += __shfl_xor(v, d, 64);
        if (l == 0) red1 = v;
    }

    // ---- Wave 0: MFMA-matvec recursion (verified) ----
    if (w == 0) {
        ABu A0, A1;
        #pragma unroll
        for (int jj = 0; jj < 8; ++jj) {
            const int kp = 4 * g + (jj & 3) + ((jj >> 2) << 4);
            float v0 = 0.f, v1 = 0.f;
            if (kp < 26) {
                v0 = __builtin_amdgcn_exp2f(t_lds[kp * 26 + c] * C_SCALE);
                if (16 + c < 26) v1 = __builtin_amdgcn_exp2f(t_lds[kp * 26 + 16 + c] * C_SCALE);
            }
            A0.u[jj] = f2bf(v0);
            A1.u[jj] = f2bf(v1);
        }

        u32x4 ev[20];
        #pragma unroll
        for (int m = 0; m < 20; ++m)
            ev[m] = *(const u32x4*)&e_lds[c * 400 + m * 20 + 4 * g];

        f32x4 s0, s1;
        #pragma unroll
        for (int i = 0; i < 4; ++i) { s0[i] = lo16f(ev[0][i]); s1[i] = hi16f(ev[0][i]); }
        if (16 + 4 * g + 0 >= 26) s1[0] = NEGF;
        if (16 + 4 * g + 1 >= 26) s1[1] = NEGF;
        if (16 + 4 * g + 2 >= 26) s1[2] = NEGF;
        if (16 + 4 * g + 3 >= 26) s1[3] = NEGF;

        const f32x4 z = {0.f, 0.f, 0.f, 0.f};
        #pragma unroll
        for (int m = 0; m < 19; ++m) {
            const float mx8 = fmaxf(fmaxf(fmaxf(s0[0], s0[1]), fmaxf(s0[2], s0[3])),
                                    fmaxf(fmaxf(s1[0], s1[1]), fmaxf(s1[2], s1[3])));
            const float mx = qmax(mx8);
            ABu B;
            B.u[0] = f2bf(__builtin_amdgcn_exp2f(s0[0] - mx));
            B.u[1] = f2bf(__builtin_amdgcn_exp2f(s0[1] - mx));
            B.u[2] = f2bf(__builtin_amdgcn_exp2f(s0[2] - mx));
            B.u[3] = f2bf(__builtin_amdgcn_exp2f(s0[3] - mx));
            B.u[4] = f2bf(__builtin_amdgcn_exp2f(s1[0] - mx));
            B.u[5] = f2bf(__builtin_amdgcn_exp2f(s1[1] - mx));
            B.u[6] = f2bf(__builtin_amdgcn_exp2f(s1[2] - mx));
            B.u[7] = f2bf(__builtin_amdgcn_exp2f(s1[3] - mx));
            f32x4 D0 = __builtin_amdgcn_mfma_f32_16x16x32_bf16(A0.b, B.b, z, 0, 0, 0);
            f32x4 D1 = __builtin_amdgcn_mfma_f32_16x16x32_bf16(A1.b, B.b, z, 0, 0, 0);
            #pragma unroll
            for (int i = 0; i < 4; ++i) {
                s0[i] = mx + __builtin_amdgcn_logf(D0[i]) + lo16f(ev[m + 1][i]);
                s1[i] = mx + __builtin_amdgcn_logf(D1[i]) + hi16f(ev[m + 1][i]);
            }
        }

        const float mxl = fmaxf(fmaxf(fmaxf(s0[0], s0[1]), fmaxf(s0[2], s0[3])),
                                fmaxf(fmaxf(s1[0], s1[1]), fmaxf(s1[2], s1[3])));
        const float mx2 = qmax(mxl);
        float sm = __builtin_amdgcn_exp2f(s0[0] - mx2) + __builtin_amdgcn_exp2f(s0[1] - mx2)
                 + __builtin_amdgcn_exp2f(s0[2] - mx2) + __builtin_amdgcn_exp2f(s0[3] - mx2)
                 + __builtin_amdgcn_exp2f(s1[0] - mx2) + __builtin_amdgcn_exp2f(s1[1] - mx2)
                 + __builtin_amdgcn_exp2f(s1[2] - mx2) + __builtin_amdgcn_exp2f(s1[3] - mx2);
        sm = qsum(sm);
        const float logZ2 = mx2 + __builtin_amdgcn_logf(sm);

        float v = (g == 0) ? LN2 * logZ2 : 0.f;
        #pragma unroll
        for (int d = 1; d <= 32; d <<= 1) v += __shfl_xor(v, d, 64);
        myv = v;
    }

    __syncthreads();   // all 4 waves alive: red1 visible to wave 0

    if (w == 0 && l == 0) part[blockIdx.x] = myv + red1;   // plain store, no atomic
}

__global__ __launch_bounds__(256) void reduce_kernel(
    const float* __restrict__ part, float* __restrict__ out, int n)
{
    __shared__ float s[4];
    const int tid = threadIdx.x;
    float v = part[tid] + part[tid + 256];
    #pragma unroll
    for (int d = 1; d <= 32; d <<= 1) v += __shfl_xor(v, d, 64);
    if ((tid & 63) == 0) s[tid >> 6] = v;
    __syncthreads();
    if (tid == 0) out[0] = s[0] + s[1] + s[2] + s[3];
}

extern "C" void kernel_launch(void* const* d_in, const int* in_sizes, int n_in,
                              void* d_out, int out_size, void* d_ws, size_t ws_size,
                              hipStream_t stream) {
    const float* X = (const float*)d_in[0];
    const int*   Y = (const int*)d_in[1];
    const float* W = (const float*)d_in[2];
    const float* T = (const float*)d_in[3];
    float* out = (float*)d_out;
    float* part = (float*)d_ws;            // 512 floats

    const int B = in_sizes[1] / 20;        // 8192
    const int nblocks = B / 16;            // 512

    crf_kernel<<<nblocks, 256, 0, stream>>>(X, Y, W, T, part);
    reduce_kernel<<<1, 256, 0, stream>>>(part, out, nblocks);
}